// Round 15
// baseline (282.404 us; speedup 1.0000x reference)
//
#include <hip/hip_runtime.h>

#define N_NODES 102000
#define D 128
#define L 12
#define E_EDGES 1000000
#define V_VOCAB 30001            // rows in word_emb (incl. padding row)
#define NEG_SLOPE 0.01f
#define NTILES (N_NODES / 16)    // 6375 exact

#define SCAN_CHUNK 1024
#define SCAN_BLOCKS ((N_NODES + SCAN_CHUNK - 1) / SCAN_CHUNK)  // 100

// CSR build partitioning: 4 dst-range groups
#define NCSR 4
#define RANGE4 (N_NODES / NCSR)  // 25500 exact

// pool slicing: 4 slices x 32 bf16 cols (one 64-B line per emb row-slice)
#define NSLC 4
#define SCOLS 32
#define WS2_STRIDE ((size_t)V_VOCAB * SCOLS)   // bf16 elems per emb slice

// fused-kernel block ranges
#define DEGI_BLOCKS 1024
#define EMB_BLOCKS ((V_VOCAB * 16 + 255) / 256)   // 1876
#define PREP_BLOCKS 32
#define SCAT_BLOCKS 1024
#define POOL_BLOCKS (NSLC * ((N_NODES * 4 + 255) / 256))  // 6376

typedef __attribute__((ext_vector_type(8))) short bf16x8;
typedef __attribute__((ext_vector_type(4))) float f32x4;
typedef __attribute__((ext_vector_type(4))) int i32x4;
typedef __attribute__((ext_vector_type(4))) unsigned int u32x4;

__device__ __forceinline__ float b2f(unsigned short u) {
    union { float f; unsigned int i; } x; x.i = ((unsigned int)u) << 16; return x.f;
}
__device__ __forceinline__ unsigned short f2b(float f) {
    unsigned int x = __float_as_uint(f);
    unsigned int r = (x + 0x7fffu + ((x >> 16) & 1u)) >> 16;
    return (unsigned short)r;
}
__device__ __forceinline__ void acc8(float* acc, uint4 v) {
    acc[0] += b2f((unsigned short)(v.x & 0xffff)); acc[1] += b2f((unsigned short)(v.x >> 16));
    acc[2] += b2f((unsigned short)(v.y & 0xffff)); acc[3] += b2f((unsigned short)(v.y >> 16));
    acc[4] += b2f((unsigned short)(v.z & 0xffff)); acc[5] += b2f((unsigned short)(v.z >> 16));
    acc[6] += b2f((unsigned short)(v.w & 0xffff)); acc[7] += b2f((unsigned short)(v.w >> 16));
}

// ---------------------------------------------------------------------------
// device bodies (shared by fused pre-pass kernels)
// ---------------------------------------------------------------------------
__device__ void degi_body(int b, const int* __restrict__ dst, int* __restrict__ deg) {
    int g = b & (NCSR - 1);
    int cb = b >> 2;
    int lo = g * RANGE4, hi = lo + RANGE4;
    const int NQ = E_EDGES / 4;
    const int stride = (DEGI_BLOCKS / NCSR) * 256;
    for (int qi = cb * 256 + threadIdx.x; qi < NQ; qi += stride) {
        i32x4 d4 = __builtin_nontemporal_load(
            reinterpret_cast<const i32x4*>(dst + qi * 4));
        if (d4.x >= lo && d4.x < hi) atomicAdd(&deg[d4.x], 1);
        if (d4.y >= lo && d4.y < hi) atomicAdd(&deg[d4.y], 1);
        if (d4.z >= lo && d4.z < hi) atomicAdd(&deg[d4.z], 1);
        if (d4.w >= lo && d4.w < hi) atomicAdd(&deg[d4.w], 1);
    }
}

__device__ void emb_body(int b, const float* __restrict__ word_emb,
                         unsigned short* __restrict__ ws) {
    int id = b * 256 + threadIdx.x;
    if (id >= V_VOCAB * 16) return;
    int r = id >> 4, q = id & 15;
    const float* p = word_emb + (size_t)r * D + q * 8;
    float4 v0 = *reinterpret_cast<const float4*>(p);
    float4 v1 = *reinterpret_cast<const float4*>(p + 4);
    u32x4 o;
    o.x = (unsigned int)f2b(v0.x) | ((unsigned int)f2b(v0.y) << 16);
    o.y = (unsigned int)f2b(v0.z) | ((unsigned int)f2b(v0.w) << 16);
    o.z = (unsigned int)f2b(v1.x) | ((unsigned int)f2b(v1.y) << 16);
    o.w = (unsigned int)f2b(v1.z) | ((unsigned int)f2b(v1.w) << 16);
    int s = q >> 2, inner = (q & 3) * 8;
    *reinterpret_cast<u32x4*>(ws + (size_t)s * WS2_STRIDE + (size_t)r * SCOLS + inner) = o;
}

__device__ void prep_w_body(int b, const float* __restrict__ W1s, const float* __restrict__ W1n,
                            const float* __restrict__ W2s, const float* __restrict__ W2n,
                            uint4* __restrict__ wf1, uint4* __restrict__ wf2) {
    int tid = b * 256 + threadIdx.x;   // 0..8191
    int layer = tid >> 12;
    int rem = tid & 4095;
    int ks = rem >> 9;
    int ct = (rem >> 6) & 7;
    int lane = rem & 63;
    const float* Ws = layer ? W2s : W1s;
    const float* Wn = layer ? W2n : W1n;
    uint4* outp = layer ? wf2 : wf1;
    int r0 = ks * 32 + (lane >> 4) * 8;
    int c = ct * 16 + (lane & 15);
    unsigned short e[8];
#pragma unroll
    for (int j = 0; j < 8; ++j) {
        int r = r0 + j;
        float v = (r < 128) ? Ws[r * 128 + c] : Wn[(r - 128) * 128 + c];
        e[j] = f2b(v);
    }
    uint4 o;
    o.x = (unsigned int)e[0] | ((unsigned int)e[1] << 16);
    o.y = (unsigned int)e[2] | ((unsigned int)e[3] << 16);
    o.z = (unsigned int)e[4] | ((unsigned int)e[5] << 16);
    o.w = (unsigned int)e[6] | ((unsigned int)e[7] << 16);
    outp[(ks * 8 + ct) * 64 + lane] = o;
}

__device__ void scatter_body(int b, const int* __restrict__ src, const int* __restrict__ dst,
                             int* __restrict__ cursor, int* __restrict__ csr_src) {
    int g = b & (NCSR - 1);
    int cb = b >> 2;
    int lo = g * RANGE4, hi = lo + RANGE4;
    const int NQ = E_EDGES / 4;
    const int stride = (SCAT_BLOCKS / NCSR) * 256;
    for (int qi = cb * 256 + threadIdx.x; qi < NQ; qi += stride) {
        i32x4 d4 = __builtin_nontemporal_load(
            reinterpret_cast<const i32x4*>(dst + qi * 4));
        i32x4 s4 = __builtin_nontemporal_load(
            reinterpret_cast<const i32x4*>(src + qi * 4));
        if (d4.x >= lo && d4.x < hi) csr_src[atomicAdd(&cursor[d4.x], 1)] = s4.x;
        if (d4.y >= lo && d4.y < hi) csr_src[atomicAdd(&cursor[d4.y], 1)] = s4.y;
        if (d4.z >= lo && d4.z < hi) csr_src[atomicAdd(&cursor[d4.z], 1)] = s4.z;
        if (d4.w >= lo && d4.w < hi) csr_src[atomicAdd(&cursor[d4.w], 1)] = s4.w;
    }
}

__device__ void pool_body(int b, const int* __restrict__ wids,
                          const float* __restrict__ lengths,
                          const unsigned short* __restrict__ ws,
                          unsigned short* __restrict__ h0) {
    int g = b & (NSLC - 1);
    int idx = (b >> 2) * 256 + threadIdx.x;
    if (idx >= N_NODES * 4) return;
    int n = idx >> 2, q = idx & 3;
    const i32x4* wp = reinterpret_cast<const i32x4*>(wids + n * L);
    i32x4 w0 = __builtin_nontemporal_load(wp + 0);
    i32x4 w1 = __builtin_nontemporal_load(wp + 1);
    i32x4 w2 = __builtin_nontemporal_load(wp + 2);
    int wid[L] = {w0.x, w0.y, w0.z, w0.w, w1.x, w1.y, w1.z, w1.w, w2.x, w2.y, w2.z, w2.w};
    const unsigned short* wsg = ws + (size_t)g * WS2_STRIDE + q * 8;
    float acc[8];
#pragma unroll
    for (int j = 0; j < 8; ++j) acc[j] = 0.f;
#pragma unroll
    for (int l = 0; l < L; ++l) {
        uint4 v = *reinterpret_cast<const uint4*>(wsg + (size_t)wid[l] * SCOLS);
        acc8(acc, v);
    }
    float inv = 1.0f / lengths[n];
    u32x4 o;
    o.x = (unsigned int)f2b(acc[0] * inv) | ((unsigned int)f2b(acc[1] * inv) << 16);
    o.y = (unsigned int)f2b(acc[2] * inv) | ((unsigned int)f2b(acc[3] * inv) << 16);
    o.z = (unsigned int)f2b(acc[4] * inv) | ((unsigned int)f2b(acc[5] * inv) << 16);
    o.w = (unsigned int)f2b(acc[6] * inv) | ((unsigned int)f2b(acc[7] * inv) << 16);
    *reinterpret_cast<u32x4*>(h0 + (size_t)n * D + g * SCOLS + q * 8) = o;
}

// ---------------------------------------------------------------------------
// A) fused: degi || emb_slice || prep_w
// ---------------------------------------------------------------------------
__global__ __launch_bounds__(256)
void build_aux_kernel(const int* __restrict__ dst, int* __restrict__ deg,
                      const float* __restrict__ word_emb, unsigned short* __restrict__ ws,
                      const float* __restrict__ W1s, const float* __restrict__ W1n,
                      const float* __restrict__ W2s, const float* __restrict__ W2n,
                      uint4* __restrict__ wf1, uint4* __restrict__ wf2) {
    int b = blockIdx.x;
    if (b < DEGI_BLOCKS) {
        degi_body(b, dst, deg);
    } else if (b < DEGI_BLOCKS + EMB_BLOCKS) {
        emb_body(b - DEGI_BLOCKS, word_emb, ws);
    } else {
        prep_w_body(b - DEGI_BLOCKS - EMB_BLOCKS, W1s, W1n, W2s, W2n, wf1, wf2);
    }
}

// ---------------------------------------------------------------------------
// B) fused: scatter || pool
// ---------------------------------------------------------------------------
__global__ __launch_bounds__(256)
void pool_scatter_kernel(const int* __restrict__ src, const int* __restrict__ dst,
                         int* __restrict__ cursor, int* __restrict__ csr_src,
                         const int* __restrict__ wids, const float* __restrict__ lengths,
                         const unsigned short* __restrict__ ws, unsigned short* __restrict__ h0) {
    int b = blockIdx.x;
    if (b < SCAT_BLOCKS) {
        scatter_body(b, src, dst, cursor, csr_src);
    } else {
        pool_body(b - SCAT_BLOCKS, wids, lengths, ws, h0);
    }
}

// ---------------------------------------------------------------------------
// 3a) per-block local exclusive scan
// ---------------------------------------------------------------------------
__global__ __launch_bounds__(256)
void scan_local_kernel(const int* __restrict__ deg, int* __restrict__ row_ptr,
                       int* __restrict__ block_sums) {
    __shared__ int wsum[4];
    int t = threadIdx.x;
    int lane = t & 63, w = t >> 6;
    int base = blockIdx.x * SCAN_CHUNK + t * 4;
    int v0 = 0, v1 = 0, v2 = 0, v3 = 0;
    if (base + 3 < N_NODES) {
        int4 v = *reinterpret_cast<const int4*>(deg + base);
        v0 = v.x; v1 = v.y; v2 = v.z; v3 = v.w;
    } else {
        if (base + 0 < N_NODES) v0 = deg[base + 0];
        if (base + 1 < N_NODES) v1 = deg[base + 1];
        if (base + 2 < N_NODES) v2 = deg[base + 2];
        if (base + 3 < N_NODES) v3 = deg[base + 3];
    }
    int s = v0 + v1 + v2 + v3;
    int x = s;
#pragma unroll
    for (int off = 1; off < 64; off <<= 1) {
        int y = __shfl_up(x, off, 64);
        if (lane >= off) x += y;
    }
    if (lane == 63) wsum[w] = x;
    __syncthreads();
    int woff = 0;
#pragma unroll
    for (int i = 0; i < 4; ++i) if (i < w) woff += wsum[i];
    int excl = woff + (x - s);
    if (base + 0 < N_NODES) row_ptr[base + 0] = excl;
    if (base + 1 < N_NODES) row_ptr[base + 1] = excl + v0;
    if (base + 2 < N_NODES) row_ptr[base + 2] = excl + v0 + v1;
    if (base + 3 < N_NODES) row_ptr[base + 3] = excl + v0 + v1 + v2;
    __syncthreads();
    if (t == 255) block_sums[blockIdx.x] = woff + x;
}

// ---------------------------------------------------------------------------
// 3b) exclusive scan of block sums (one wave)
// ---------------------------------------------------------------------------
__global__ __launch_bounds__(64)
void scan_blocks_kernel(int* __restrict__ block_sums, int* __restrict__ row_ptr) {
    int lane = threadIdx.x;
    int e0 = (2 * lane + 0 < SCAN_BLOCKS) ? block_sums[2 * lane + 0] : 0;
    int e1 = (2 * lane + 1 < SCAN_BLOCKS) ? block_sums[2 * lane + 1] : 0;
    int s = e0 + e1;
    int x = s;
#pragma unroll
    for (int off = 1; off < 64; off <<= 1) {
        int y = __shfl_up(x, off, 64);
        if (lane >= off) x += y;
    }
    int excl = x - s;
    if (2 * lane + 0 < SCAN_BLOCKS) block_sums[2 * lane + 0] = excl;
    if (2 * lane + 1 < SCAN_BLOCKS) block_sums[2 * lane + 1] = excl + e0;
    if (lane == 63) row_ptr[N_NODES] = x;
}

// ---------------------------------------------------------------------------
// 3c) fixup + cursor copy
// ---------------------------------------------------------------------------
__global__ __launch_bounds__(256)
void scan_fixup_kernel(int* __restrict__ row_ptr, const int* __restrict__ block_sums,
                       int* __restrict__ cursor) {
    int base = blockIdx.x * SCAN_CHUNK + threadIdx.x * 4;
    int boff = block_sums[blockIdx.x];
#pragma unroll
    for (int j = 0; j < 4; ++j) {
        int i = base + j;
        if (i < N_NODES) {
            int v = row_ptr[i] + boff;
            row_ptr[i] = v;
            cursor[i] = v;
        }
    }
}

// ---------------------------------------------------------------------------
// C) fused SAGE layer: per wave, (1) gather-mean its 16 rows into LDS
//    (XOR-swizzled bf16 tile), barrier, (2) MFMA [h | agg] @ [Ws; Wn] + b.
//    W fragments read from GLOBAL (64 KB, L2-resident) -> LDS is only 16 KB,
//    keeping occupancy high for the latency-bound gather phase.
//    Out-of-place (hI read-only) -> no in-place hazard.
// ---------------------------------------------------------------------------
template <int RELU, typename OutT>
__global__ __launch_bounds__(256)
void sage_layer_kernel(const int* __restrict__ row_ptr, const int* __restrict__ csr_src,
                       const unsigned short* __restrict__ hI,
                       const uint4* __restrict__ wfrag, const float* __restrict__ bias,
                       OutT* __restrict__ outp) {
    __shared__ unsigned short aggT[4][16 * D];   // 16 KB
    int t = threadIdx.x;
    int lane = t & 63, w = t >> 6;
    int rt = blockIdx.x * 4 + w;
    bool active = (rt < NTILES);
    int row0 = rt * 16;

    // ---- phase 1: gather agg for rows row0..row0+15 into aggT[w] ----
    if (active) {
        int q = lane & 15;                       // 16B chunk within row
        const unsigned short* hq = hI + q * 8;
#pragma unroll
        for (int it = 0; it < 4; ++it) {
            int rloc = (lane >> 4) * 4 + it;     // 0..15 (4 nodes in flight)
            int n = row0 + rloc;
            int beg = row_ptr[n], end = row_ptr[n + 1];
            float acc[8];
#pragma unroll
            for (int j = 0; j < 8; ++j) acc[j] = 0.f;
            int p = beg;
            for (; p + 4 <= end; p += 4) {
                int s0 = csr_src[p + 0];
                int s1 = csr_src[p + 1];
                int s2 = csr_src[p + 2];
                int s3 = csr_src[p + 3];
                uint4 v0 = *reinterpret_cast<const uint4*>(hq + (size_t)s0 * D);
                uint4 v1 = *reinterpret_cast<const uint4*>(hq + (size_t)s1 * D);
                uint4 v2 = *reinterpret_cast<const uint4*>(hq + (size_t)s2 * D);
                uint4 v3 = *reinterpret_cast<const uint4*>(hq + (size_t)s3 * D);
                acc8(acc, v0); acc8(acc, v1); acc8(acc, v2); acc8(acc, v3);
            }
            for (; p < end; ++p) {
                int s = csr_src[p];
                acc8(acc, *reinterpret_cast<const uint4*>(hq + (size_t)s * D));
            }
            int dcount = end - beg;
            float inv = 1.0f / (float)(dcount > 1 ? dcount : 1);
            u32x4 o;
            o.x = (unsigned int)f2b(acc[0] * inv) | ((unsigned int)f2b(acc[1] * inv) << 16);
            o.y = (unsigned int)f2b(acc[2] * inv) | ((unsigned int)f2b(acc[3] * inv) << 16);
            o.z = (unsigned int)f2b(acc[4] * inv) | ((unsigned int)f2b(acc[5] * inv) << 16);
            o.w = (unsigned int)f2b(acc[6] * inv) | ((unsigned int)f2b(acc[7] * inv) << 16);
            int byte = (rloc * 256 + q * 16) ^ ((rloc & 7) << 4);   // XOR swizzle (G4)
            *reinterpret_cast<u32x4*>(
                reinterpret_cast<char*>(&aggT[w][0]) + byte) = o;
        }
    }
    __syncthreads();   // aggT ready (also orders LDS writes before reads)

    // ---- phase 2: MFMA ----
    if (active) {
        int arow = row0 + (lane & 15);
        int koff = (lane >> 4) * 8;
        const unsigned short* hp = hI + (size_t)arow * D + koff;
        bf16x8 a[8];
#pragma unroll
        for (int ks = 0; ks < 4; ++ks) a[ks] = *reinterpret_cast<const bf16x8*>(hp + ks * 32);
#pragma unroll
        for (int ks = 0; ks < 4; ++ks) {
            int rloc = lane & 15;
            int q2 = ks * 4 + (lane >> 4);       // 16B chunk holding cols [ks*32+koff, +8)
            int byte = (rloc * 256 + q2 * 16) ^ ((rloc & 7) << 4);
            a[4 + ks] = *reinterpret_cast<const bf16x8*>(
                reinterpret_cast<const char*>(&aggT[w][0]) + byte);
        }
        int crow = row0 + (lane >> 4) * 4;
        int ccol0 = lane & 15;
#pragma unroll
        for (int ct = 0; ct < 8; ++ct) {
            f32x4 acc = {0.f, 0.f, 0.f, 0.f};
#pragma unroll
            for (int ks = 0; ks < 8; ++ks) {
                bf16x8 b = *reinterpret_cast<const bf16x8*>(&wfrag[(ks * 8 + ct) * 64 + lane]);
                acc = __builtin_amdgcn_mfma_f32_16x16x32_bf16(a[ks], b, acc, 0, 0, 0);
            }
            int col = ct * 16 + ccol0;
            float bv = bias[col];
#pragma unroll
            for (int i = 0; i < 4; ++i) {
                float v = acc[i] + bv;
                if (RELU) v = (v > 0.f) ? v : NEG_SLOPE * v;
                if constexpr (sizeof(OutT) == 2) {
                    outp[(size_t)(crow + i) * D + col] = (OutT)f2b(v);
                } else {
                    outp[(size_t)(crow + i) * D + col] = v;
                }
            }
        }
    }
}

extern "C" void kernel_launch(void* const* d_in, const int* in_sizes, int n_in,
                              void* d_out, int out_size, void* d_ws, size_t ws_size,
                              hipStream_t stream) {
    const int*   wids     = (const int*)d_in[0];
    const float* lengths  = (const float*)d_in[1];
    const int*   src      = (const int*)d_in[2];
    const int*   dst      = (const int*)d_in[3];
    const float* word_emb = (const float*)d_in[4];
    const float* W1s      = (const float*)d_in[5];
    const float* W1n      = (const float*)d_in[6];
    const float* b1       = (const float*)d_in[7];
    const float* W2s      = (const float*)d_in[8];
    const float* W2n      = (const float*)d_in[9];
    const float* b2       = (const float*)d_in[10];

    // d_ws layout
    unsigned short* h0  = (unsigned short*)d_ws;               // N*D bf16
    unsigned short* h1  = h0 + (size_t)N_NODES * D;            // N*D bf16 (layer-1 out)
    uint4* wf1 = (uint4*)(h1 + (size_t)N_NODES * D);           // 4096 uint4
    uint4* wf2 = wf1 + 4096;                                   // 4096 uint4
    int* deg_i      = (int*)(wf2 + 4096);                      // N
    int* row_ptr    = deg_i + N_NODES;                         // N+1
    int* cursor     = row_ptr + (N_NODES + 1);                 // N
    int* block_sums = cursor + N_NODES;                        // SCAN_BLOCKS
    int* csr_src    = block_sums + ((SCAN_BLOCKS + 3) & ~3);   // E

    // bf16 sliced emb staged in d_out (7.7 MB of 52 MB; free until final write)
    unsigned short* ws_emb = (unsigned short*)d_out;

    (void)hipMemsetAsync(deg_i, 0, N_NODES * sizeof(int), stream);

    // A: degi || emb_slice || prep_w
    build_aux_kernel<<<DEGI_BLOCKS + EMB_BLOCKS + PREP_BLOCKS, 256, 0, stream>>>(
        dst, deg_i, word_emb, ws_emb, W1s, W1n, W2s, W2n, wf1, wf2);

    // scans
    scan_local_kernel<<<SCAN_BLOCKS, 256, 0, stream>>>(deg_i, row_ptr, block_sums);
    scan_blocks_kernel<<<1, 64, 0, stream>>>(block_sums, row_ptr);
    scan_fixup_kernel<<<SCAN_BLOCKS, 256, 0, stream>>>(row_ptr, block_sums, cursor);

    // B: scatter || pool
    pool_scatter_kernel<<<SCAT_BLOCKS + POOL_BLOCKS, 256, 0, stream>>>(
        src, dst, cursor, csr_src, wids, lengths, ws_emb, h0);

    const int LAYER_GRID = (NTILES + 3) / 4;   // 1594
    // layer 1: h0 -> h1 (fused gather+linear, leaky-relu)
    sage_layer_kernel<1, unsigned short><<<LAYER_GRID, 256, 0, stream>>>(
        row_ptr, csr_src, h0, wf1, b1, h1);
    // layer 2: h1 -> d_out f32 (overwrites staged emb)
    sage_layer_kernel<0, float><<<LAYER_GRID, 256, 0, stream>>>(
        row_ptr, csr_src, h1, wf2, b2, (float*)d_out);
}

// Round 16
// 221.242 us; speedup vs baseline: 1.2764x; 1.2764x over previous
//
#include <hip/hip_runtime.h>

#define N_NODES 102000
#define D 128
#define L 12
#define E_EDGES 1000000
#define V_VOCAB 30001            // rows in word_emb (incl. padding row)
#define NEG_SLOPE 0.01f
#define NTILES (N_NODES / 16)    // 6375 exact

// padded CSR: fixed CAP slots per node (deg ~ Poisson(9.8); P(deg>=48)~2e-18)
#define CAP 48

// CSR build partitioning: 4 dst-range groups
#define NCSR 4
#define RANGE4 (N_NODES / NCSR)  // 25500 exact

// pool slicing: 4 slices x 32 bf16 cols (one 64-B line per emb row-slice)
#define NSLC 4
#define SCOLS 32
#define WS2_STRIDE ((size_t)V_VOCAB * SCOLS)   // bf16 elems per emb slice

// fused-kernel block ranges
#define EMB_BLOCKS ((V_VOCAB * 16 + 255) / 256)   // 1876
#define PREP_BLOCKS 32
#define SCAT_BLOCKS 1024
#define POOL_BLOCKS (NSLC * ((N_NODES * 4 + 255) / 256))  // 6376

typedef __attribute__((ext_vector_type(8))) short bf16x8;
typedef __attribute__((ext_vector_type(4))) float f32x4;
typedef __attribute__((ext_vector_type(4))) int i32x4;
typedef __attribute__((ext_vector_type(4))) unsigned int u32x4;

__device__ __forceinline__ float b2f(unsigned short u) {
    union { float f; unsigned int i; } x; x.i = ((unsigned int)u) << 16; return x.f;
}
__device__ __forceinline__ unsigned short f2b(float f) {
    unsigned int x = __float_as_uint(f);
    unsigned int r = (x + 0x7fffu + ((x >> 16) & 1u)) >> 16;
    return (unsigned short)r;
}
__device__ __forceinline__ void acc8(float* acc, uint4 v) {
    acc[0] += b2f((unsigned short)(v.x & 0xffff)); acc[1] += b2f((unsigned short)(v.x >> 16));
    acc[2] += b2f((unsigned short)(v.y & 0xffff)); acc[3] += b2f((unsigned short)(v.y >> 16));
    acc[4] += b2f((unsigned short)(v.z & 0xffff)); acc[5] += b2f((unsigned short)(v.z >> 16));
    acc[6] += b2f((unsigned short)(v.w & 0xffff)); acc[7] += b2f((unsigned short)(v.w >> 16));
}

// ---------------------------------------------------------------------------
// device bodies
// ---------------------------------------------------------------------------
__device__ void emb_body(int b, const float* __restrict__ word_emb,
                         unsigned short* __restrict__ ws) {
    int id = b * 256 + threadIdx.x;
    if (id >= V_VOCAB * 16) return;
    int r = id >> 4, q = id & 15;
    const float* p = word_emb + (size_t)r * D + q * 8;
    float4 v0 = *reinterpret_cast<const float4*>(p);
    float4 v1 = *reinterpret_cast<const float4*>(p + 4);
    u32x4 o;
    o.x = (unsigned int)f2b(v0.x) | ((unsigned int)f2b(v0.y) << 16);
    o.y = (unsigned int)f2b(v0.z) | ((unsigned int)f2b(v0.w) << 16);
    o.z = (unsigned int)f2b(v1.x) | ((unsigned int)f2b(v1.y) << 16);
    o.w = (unsigned int)f2b(v1.z) | ((unsigned int)f2b(v1.w) << 16);
    int s = q >> 2, inner = (q & 3) * 8;
    *reinterpret_cast<u32x4*>(ws + (size_t)s * WS2_STRIDE + (size_t)r * SCOLS + inner) = o;
}

__device__ void prep_w_body(int b, const float* __restrict__ W1s, const float* __restrict__ W1n,
                            const float* __restrict__ W2s, const float* __restrict__ W2n,
                            uint4* __restrict__ wf1, uint4* __restrict__ wf2) {
    int tid = b * 256 + threadIdx.x;   // 0..8191
    int layer = tid >> 12;
    int rem = tid & 4095;
    int ks = rem >> 9;
    int ct = (rem >> 6) & 7;
    int lane = rem & 63;
    const float* Ws = layer ? W2s : W1s;
    const float* Wn = layer ? W2n : W1n;
    uint4* outp = layer ? wf2 : wf1;
    int r0 = ks * 32 + (lane >> 4) * 8;
    int c = ct * 16 + (lane & 15);
    unsigned short e[8];
#pragma unroll
    for (int j = 0; j < 8; ++j) {
        int r = r0 + j;
        float v = (r < 128) ? Ws[r * 128 + c] : Wn[(r - 128) * 128 + c];
        e[j] = f2b(v);
    }
    uint4 o;
    o.x = (unsigned int)e[0] | ((unsigned int)e[1] << 16);
    o.y = (unsigned int)e[2] | ((unsigned int)e[3] << 16);
    o.z = (unsigned int)e[4] | ((unsigned int)e[5] << 16);
    o.w = (unsigned int)e[6] | ((unsigned int)e[7] << 16);
    outp[(ks * 8 + ct) * 64 + lane] = o;
}

// padded-CSR scatter: no row_ptr needed; pos straight from per-node counter
__device__ void scatter_body(int b, const int* __restrict__ src, const int* __restrict__ dst,
                             int* __restrict__ cnt, int* __restrict__ csr_pad) {
    int g = b & (NCSR - 1);
    int cb = b >> 2;
    int lo = g * RANGE4, hi = lo + RANGE4;
    const int NQ = E_EDGES / 4;
    const int stride = (SCAT_BLOCKS / NCSR) * 256;
    for (int qi = cb * 256 + threadIdx.x; qi < NQ; qi += stride) {
        i32x4 d4 = __builtin_nontemporal_load(
            reinterpret_cast<const i32x4*>(dst + qi * 4));
        i32x4 s4 = __builtin_nontemporal_load(
            reinterpret_cast<const i32x4*>(src + qi * 4));
        if (d4.x >= lo && d4.x < hi) {
            int p = atomicAdd(&cnt[d4.x], 1);
            if (p < CAP) csr_pad[d4.x * CAP + p] = s4.x;
        }
        if (d4.y >= lo && d4.y < hi) {
            int p = atomicAdd(&cnt[d4.y], 1);
            if (p < CAP) csr_pad[d4.y * CAP + p] = s4.y;
        }
        if (d4.z >= lo && d4.z < hi) {
            int p = atomicAdd(&cnt[d4.z], 1);
            if (p < CAP) csr_pad[d4.z * CAP + p] = s4.z;
        }
        if (d4.w >= lo && d4.w < hi) {
            int p = atomicAdd(&cnt[d4.w], 1);
            if (p < CAP) csr_pad[d4.w * CAP + p] = s4.w;
        }
    }
}

__device__ void pool_body(int b, const int* __restrict__ wids,
                          const float* __restrict__ lengths,
                          const unsigned short* __restrict__ ws,
                          unsigned short* __restrict__ h0) {
    int g = b & (NSLC - 1);
    int idx = (b >> 2) * 256 + threadIdx.x;
    if (idx >= N_NODES * 4) return;
    int n = idx >> 2, q = idx & 3;
    const i32x4* wp = reinterpret_cast<const i32x4*>(wids + n * L);
    i32x4 w0 = __builtin_nontemporal_load(wp + 0);
    i32x4 w1 = __builtin_nontemporal_load(wp + 1);
    i32x4 w2 = __builtin_nontemporal_load(wp + 2);
    int wid[L] = {w0.x, w0.y, w0.z, w0.w, w1.x, w1.y, w1.z, w1.w, w2.x, w2.y, w2.z, w2.w};
    const unsigned short* wsg = ws + (size_t)g * WS2_STRIDE + q * 8;
    float acc[8];
#pragma unroll
    for (int j = 0; j < 8; ++j) acc[j] = 0.f;
#pragma unroll
    for (int l = 0; l < L; ++l) {
        uint4 v = *reinterpret_cast<const uint4*>(wsg + (size_t)wid[l] * SCOLS);
        acc8(acc, v);
    }
    float inv = 1.0f / lengths[n];
    u32x4 o;
    o.x = (unsigned int)f2b(acc[0] * inv) | ((unsigned int)f2b(acc[1] * inv) << 16);
    o.y = (unsigned int)f2b(acc[2] * inv) | ((unsigned int)f2b(acc[3] * inv) << 16);
    o.z = (unsigned int)f2b(acc[4] * inv) | ((unsigned int)f2b(acc[5] * inv) << 16);
    o.w = (unsigned int)f2b(acc[6] * inv) | ((unsigned int)f2b(acc[7] * inv) << 16);
    *reinterpret_cast<u32x4*>(h0 + (size_t)n * D + g * SCOLS + q * 8) = o;
}

// ---------------------------------------------------------------------------
// A) fused: emb_slice || prep_w
// ---------------------------------------------------------------------------
__global__ __launch_bounds__(256)
void build_aux_kernel(const float* __restrict__ word_emb, unsigned short* __restrict__ ws,
                      const float* __restrict__ W1s, const float* __restrict__ W1n,
                      const float* __restrict__ W2s, const float* __restrict__ W2n,
                      uint4* __restrict__ wf1, uint4* __restrict__ wf2) {
    int b = blockIdx.x;
    if (b < EMB_BLOCKS) {
        emb_body(b, word_emb, ws);
    } else {
        prep_w_body(b - EMB_BLOCKS, W1s, W1n, W2s, W2n, wf1, wf2);
    }
}

// ---------------------------------------------------------------------------
// B) fused: padded-CSR scatter || pool
// ---------------------------------------------------------------------------
__global__ __launch_bounds__(256)
void pool_scatter_kernel(const int* __restrict__ src, const int* __restrict__ dst,
                         int* __restrict__ cnt, int* __restrict__ csr_pad,
                         const int* __restrict__ wids, const float* __restrict__ lengths,
                         const unsigned short* __restrict__ ws, unsigned short* __restrict__ h0) {
    int b = blockIdx.x;
    if (b < SCAT_BLOCKS) {
        scatter_body(b, src, dst, cnt, csr_pad);
    } else {
        pool_body(b - SCAT_BLOCKS, wids, lengths, ws, h0);
    }
}

// ---------------------------------------------------------------------------
// 6) gather-aggregate (padded CSR), interleaved layout, 16 lanes/node, 4-ILP
// ---------------------------------------------------------------------------
__global__ void gather_agg_kernel(const int* __restrict__ cnt,
                                  const int* __restrict__ csr_pad,
                                  const unsigned short* __restrict__ hI,
                                  unsigned short* __restrict__ aggI) {
    int idx = blockIdx.x * 256 + threadIdx.x;   // 0 .. N*16-1
    int n = idx >> 4, q = idx & 15;             // q = 16B chunk
    if (n >= N_NODES) return;
    const unsigned short* hq = hI + q * 8;
    int dcount = cnt[n];
    int m = dcount < CAP ? dcount : CAP;
    int beg = n * CAP, end = beg + m;
    float acc[8];
#pragma unroll
    for (int j = 0; j < 8; ++j) acc[j] = 0.f;
    int p = beg;
    for (; p + 4 <= end; p += 4) {
        int s0 = csr_pad[p + 0];
        int s1 = csr_pad[p + 1];
        int s2 = csr_pad[p + 2];
        int s3 = csr_pad[p + 3];
        uint4 v0 = *reinterpret_cast<const uint4*>(hq + (size_t)s0 * D);
        uint4 v1 = *reinterpret_cast<const uint4*>(hq + (size_t)s1 * D);
        uint4 v2 = *reinterpret_cast<const uint4*>(hq + (size_t)s2 * D);
        uint4 v3 = *reinterpret_cast<const uint4*>(hq + (size_t)s3 * D);
        acc8(acc, v0); acc8(acc, v1); acc8(acc, v2); acc8(acc, v3);
    }
    for (; p < end; ++p) {
        int s = csr_pad[p];
        acc8(acc, *reinterpret_cast<const uint4*>(hq + (size_t)s * D));
    }
    float inv = 1.0f / (float)(dcount > 1 ? dcount : 1);
    u32x4 o;
    o.x = (unsigned int)f2b(acc[0] * inv) | ((unsigned int)f2b(acc[1] * inv) << 16);
    o.y = (unsigned int)f2b(acc[2] * inv) | ((unsigned int)f2b(acc[3] * inv) << 16);
    o.z = (unsigned int)f2b(acc[4] * inv) | ((unsigned int)f2b(acc[5] * inv) << 16);
    o.w = (unsigned int)f2b(acc[6] * inv) | ((unsigned int)f2b(acc[7] * inv) << 16);
    *reinterpret_cast<u32x4*>(aggI + (size_t)n * D + q * 8) = o;
}

// ---------------------------------------------------------------------------
// 7) out = [h | agg] @ [Ws; Wn] + b  via mfma_f32_16x16x32_bf16 (interleaved).
//    In-place (outp==hI, layer 1) safe: each wave loads only its own 16 rows
//    before any store; waves/blocks own disjoint rows. No __restrict__.
// ---------------------------------------------------------------------------
template <int RELU, typename OutT>
__global__ __launch_bounds__(256, 2)
void linear_mfma_kernel(const unsigned short* hI, const unsigned short* aggI,
                        const uint4* wfrag, const float* bias, OutT* outp) {
    __shared__ uint4 wlds[4096];   // 64 KB
    int t = threadIdx.x;
#pragma unroll
    for (int i = 0; i < 16; ++i) wlds[t + i * 256] = wfrag[t + i * 256];
    __syncthreads();
    int lane = t & 63, w = t >> 6;
    int rt = blockIdx.x * 4 + w;
    if (rt >= NTILES) return;      // no barriers after this point
    int row0 = rt * 16;
    int arow = row0 + (lane & 15);
    int koff = (lane >> 4) * 8;
    const unsigned short* hp = hI + (size_t)arow * D + koff;
    const unsigned short* ap = aggI + (size_t)arow * D + koff;
    bf16x8 a[8];
#pragma unroll
    for (int ks = 0; ks < 4; ++ks) a[ks] = *reinterpret_cast<const bf16x8*>(hp + ks * 32);
#pragma unroll
    for (int ks = 0; ks < 4; ++ks) a[4 + ks] = *reinterpret_cast<const bf16x8*>(ap + ks * 32);
    int crow = row0 + (lane >> 4) * 4;
    int ccol0 = lane & 15;
#pragma unroll
    for (int ct = 0; ct < 8; ++ct) {
        f32x4 acc = {0.f, 0.f, 0.f, 0.f};
#pragma unroll
        for (int ks = 0; ks < 8; ++ks) {
            bf16x8 b = *reinterpret_cast<const bf16x8*>(&wlds[(ks * 8 + ct) * 64 + lane]);
            acc = __builtin_amdgcn_mfma_f32_16x16x32_bf16(a[ks], b, acc, 0, 0, 0);
        }
        int col = ct * 16 + ccol0;
        float bv = bias[col];
#pragma unroll
        for (int i = 0; i < 4; ++i) {
            float v = acc[i] + bv;
            if (RELU) v = (v > 0.f) ? v : NEG_SLOPE * v;
            if constexpr (sizeof(OutT) == 2) {
                outp[(size_t)(crow + i) * D + col] = (OutT)f2b(v);
            } else {
                outp[(size_t)(crow + i) * D + col] = v;
            }
        }
    }
}

extern "C" void kernel_launch(void* const* d_in, const int* in_sizes, int n_in,
                              void* d_out, int out_size, void* d_ws, size_t ws_size,
                              hipStream_t stream) {
    const int*   wids     = (const int*)d_in[0];
    const float* lengths  = (const float*)d_in[1];
    const int*   src      = (const int*)d_in[2];
    const int*   dst      = (const int*)d_in[3];
    const float* word_emb = (const float*)d_in[4];
    const float* W1s      = (const float*)d_in[5];
    const float* W1n      = (const float*)d_in[6];
    const float* b1       = (const float*)d_in[7];
    const float* W2s      = (const float*)d_in[8];
    const float* W2n      = (const float*)d_in[9];
    const float* b2       = (const float*)d_in[10];

    // d_ws layout
    unsigned short* h0  = (unsigned short*)d_ws;               // N*D bf16
    unsigned short* agg = h0 + (size_t)N_NODES * D;            // N*D bf16
    uint4* wf1 = (uint4*)(agg + (size_t)N_NODES * D);          // 4096 uint4
    uint4* wf2 = wf1 + 4096;                                   // 4096 uint4
    int* cnt = (int*)(wf2 + 4096);                             // N

    // d_out staging (dead until the final layer-2 write):
    //   [0, 7.7MB): bf16 sliced emb; [8MB, 8MB+19.6MB): padded CSR
    unsigned short* ws_emb = (unsigned short*)d_out;
    int* csr_pad = (int*)((char*)d_out + (8u << 20));

    (void)hipMemsetAsync(cnt, 0, N_NODES * sizeof(int), stream);

    // A: emb_slice || prep_w
    build_aux_kernel<<<EMB_BLOCKS + PREP_BLOCKS, 256, 0, stream>>>(
        word_emb, ws_emb, W1s, W1n, W2s, W2n, wf1, wf2);

    // B: padded-CSR scatter || pool
    pool_scatter_kernel<<<SCAT_BLOCKS + POOL_BLOCKS, 256, 0, stream>>>(
        src, dst, cnt, csr_pad, wids, lengths, ws_emb, h0);

    const int GATHER_GRID = (N_NODES * 16) / 256;              // 6375
    const int LIN_GRID = (NTILES + 3) / 4;                     // 1594
    // layer 1 (in-place h0 -> h0)
    gather_agg_kernel<<<GATHER_GRID, 256, 0, stream>>>(cnt, csr_pad, h0, agg);
    linear_mfma_kernel<1, unsigned short><<<LIN_GRID, 256, 0, stream>>>(h0, agg, wf1, b1, h0);
    // layer 2 (f32 out -> d_out; csr_pad/emb regions are dead by then)
    gather_agg_kernel<<<GATHER_GRID, 256, 0, stream>>>(cnt, csr_pad, h0, agg);
    linear_mfma_kernel<0, float><<<LIN_GRID, 256, 0, stream>>>(h0, agg, wf2, b2, (float*)d_out);
}

// Round 17
// 217.539 us; speedup vs baseline: 1.2982x; 1.0170x over previous
//
#include <hip/hip_runtime.h>

#define N_NODES 102000
#define D 128
#define L 12
#define E_EDGES 1000000
#define V_VOCAB 30001            // rows in word_emb (incl. padding row)
#define NEG_SLOPE 0.01f
#define NTILES (N_NODES / 16)    // 6375 exact

// padded CSR: fixed CAP slots per node (deg ~ Poisson(9.8); P(deg>=48)~2e-18)
#define CAP 48

// bucketed CSR build
#define RB 256                                    // nodes per bucket
#define NBUCK ((N_NODES + RB - 1) / RB)           // 399
#define BCAP 2944                                 // mean 2510 + ~8.7 sigma
#define P1_BLOCKS ((E_EDGES + 1023) / 1024)       // 977

// pool slicing: 4 slices x 32 bf16 cols (one 64-B line per emb row-slice)
#define NSLC 4
#define SCOLS 32
#define WS2_STRIDE ((size_t)V_VOCAB * SCOLS)      // bf16 elems per emb slice

// fused-kernel block ranges
#define EMB_BLOCKS ((V_VOCAB * 16 + 255) / 256)   // 1876
#define PREP_BLOCKS 32
#define POOL_BLOCKS (NSLC * ((N_NODES * 4 + 255) / 256))  // 6376

#define LIN_BLOCKS 512

typedef __attribute__((ext_vector_type(8))) short bf16x8;
typedef __attribute__((ext_vector_type(4))) float f32x4;
typedef __attribute__((ext_vector_type(4))) int i32x4;
typedef __attribute__((ext_vector_type(4))) unsigned int u32x4;

__device__ __forceinline__ float b2f(unsigned short u) {
    union { float f; unsigned int i; } x; x.i = ((unsigned int)u) << 16; return x.f;
}
__device__ __forceinline__ unsigned short f2b(float f) {
    unsigned int x = __float_as_uint(f);
    unsigned int r = (x + 0x7fffu + ((x >> 16) & 1u)) >> 16;
    return (unsigned short)r;
}
__device__ __forceinline__ void acc8(float* acc, uint4 v) {
    acc[0] += b2f((unsigned short)(v.x & 0xffff)); acc[1] += b2f((unsigned short)(v.x >> 16));
    acc[2] += b2f((unsigned short)(v.y & 0xffff)); acc[3] += b2f((unsigned short)(v.y >> 16));
    acc[4] += b2f((unsigned short)(v.z & 0xffff)); acc[5] += b2f((unsigned short)(v.z >> 16));
    acc[6] += b2f((unsigned short)(v.w & 0xffff)); acc[7] += b2f((unsigned short)(v.w >> 16));
}

// ---------------------------------------------------------------------------
// device bodies
// ---------------------------------------------------------------------------
__device__ void emb_body(int b, const float* __restrict__ word_emb,
                         unsigned short* __restrict__ ws) {
    int id = b * 256 + threadIdx.x;
    if (id >= V_VOCAB * 16) return;
    int r = id >> 4, q = id & 15;
    const float* p = word_emb + (size_t)r * D + q * 8;
    float4 v0 = *reinterpret_cast<const float4*>(p);
    float4 v1 = *reinterpret_cast<const float4*>(p + 4);
    u32x4 o;
    o.x = (unsigned int)f2b(v0.x) | ((unsigned int)f2b(v0.y) << 16);
    o.y = (unsigned int)f2b(v0.z) | ((unsigned int)f2b(v0.w) << 16);
    o.z = (unsigned int)f2b(v1.x) | ((unsigned int)f2b(v1.y) << 16);
    o.w = (unsigned int)f2b(v1.z) | ((unsigned int)f2b(v1.w) << 16);
    int s = q >> 2, inner = (q & 3) * 8;
    *reinterpret_cast<u32x4*>(ws + (size_t)s * WS2_STRIDE + (size_t)r * SCOLS + inner) = o;
}

__device__ void prep_w_body(int b, const float* __restrict__ W1s, const float* __restrict__ W1n,
                            const float* __restrict__ W2s, const float* __restrict__ W2n,
                            uint4* __restrict__ wf1, uint4* __restrict__ wf2) {
    int tid = b * 256 + threadIdx.x;   // 0..8191
    int layer = tid >> 12;
    int rem = tid & 4095;
    int ks = rem >> 9;
    int ct = (rem >> 6) & 7;
    int lane = rem & 63;
    const float* Ws = layer ? W2s : W1s;
    const float* Wn = layer ? W2n : W1n;
    uint4* outp = layer ? wf2 : wf1;
    int r0 = ks * 32 + (lane >> 4) * 8;
    int c = ct * 16 + (lane & 15);
    unsigned short e[8];
#pragma unroll
    for (int j = 0; j < 8; ++j) {
        int r = r0 + j;
        float v = (r < 128) ? Ws[r * 128 + c] : Wn[(r - 128) * 128 + c];
        e[j] = f2b(v);
    }
    uint4 o;
    o.x = (unsigned int)e[0] | ((unsigned int)e[1] << 16);
    o.y = (unsigned int)e[2] | ((unsigned int)e[3] << 16);
    o.z = (unsigned int)e[4] | ((unsigned int)e[5] << 16);
    o.w = (unsigned int)e[6] | ((unsigned int)e[7] << 16);
    outp[(ks * 8 + ct) * 64 + lane] = o;
}

// pass 1: LDS-histogram bucket append (no global RMW chains)
__device__ void pass1_body(int b, const int* __restrict__ src, const int* __restrict__ dst,
                           int* __restrict__ bucket_cnt, int2* __restrict__ bucket_buf) {
    __shared__ int hist[NBUCK];
    __shared__ int base[NBUCK];
    int t = threadIdx.x;
    for (int i = t; i < NBUCK; i += 256) hist[i] = 0;
    __syncthreads();
    int e0 = b * 1024 + t * 4;
    i32x4 d4, s4;
    bool valid = (e0 < E_EDGES);            // E % 4 == 0 -> quad fully valid
    if (valid) {
        d4 = __builtin_nontemporal_load(reinterpret_cast<const i32x4*>(dst + e0));
        s4 = __builtin_nontemporal_load(reinterpret_cast<const i32x4*>(src + e0));
        atomicAdd(&hist[d4.x >> 8], 1);
        atomicAdd(&hist[d4.y >> 8], 1);
        atomicAdd(&hist[d4.z >> 8], 1);
        atomicAdd(&hist[d4.w >> 8], 1);
    }
    __syncthreads();
    for (int i = t; i < NBUCK; i += 256) {
        int h = hist[i];
        base[i] = h ? atomicAdd(&bucket_cnt[i], h) : 0;
        hist[i] = 0;                        // reuse as cursor
    }
    __syncthreads();
    if (valid) {
        int bb, p;
        bb = d4.x >> 8; p = base[bb] + atomicAdd(&hist[bb], 1);
        if (p < BCAP) bucket_buf[(size_t)bb * BCAP + p] = make_int2(d4.x, s4.x);
        bb = d4.y >> 8; p = base[bb] + atomicAdd(&hist[bb], 1);
        if (p < BCAP) bucket_buf[(size_t)bb * BCAP + p] = make_int2(d4.y, s4.y);
        bb = d4.z >> 8; p = base[bb] + atomicAdd(&hist[bb], 1);
        if (p < BCAP) bucket_buf[(size_t)bb * BCAP + p] = make_int2(d4.z, s4.z);
        bb = d4.w >> 8; p = base[bb] + atomicAdd(&hist[bb], 1);
        if (p < BCAP) bucket_buf[(size_t)bb * BCAP + p] = make_int2(d4.w, s4.w);
    }
}

__device__ void pool_body(int b, const int* __restrict__ wids,
                          const float* __restrict__ lengths,
                          const unsigned short* __restrict__ ws,
                          unsigned short* __restrict__ h0) {
    int g = b & (NSLC - 1);
    int idx = (b >> 2) * 256 + threadIdx.x;
    if (idx >= N_NODES * 4) return;
    int n = idx >> 2, q = idx & 3;
    const i32x4* wp = reinterpret_cast<const i32x4*>(wids + n * L);
    i32x4 w0 = __builtin_nontemporal_load(wp + 0);
    i32x4 w1 = __builtin_nontemporal_load(wp + 1);
    i32x4 w2 = __builtin_nontemporal_load(wp + 2);
    int wid[L] = {w0.x, w0.y, w0.z, w0.w, w1.x, w1.y, w1.z, w1.w, w2.x, w2.y, w2.z, w2.w};
    const unsigned short* wsg = ws + (size_t)g * WS2_STRIDE + q * 8;
    float acc[8];
#pragma unroll
    for (int j = 0; j < 8; ++j) acc[j] = 0.f;
#pragma unroll
    for (int l = 0; l < L; ++l) {
        uint4 v = *reinterpret_cast<const uint4*>(wsg + (size_t)wid[l] * SCOLS);
        acc8(acc, v);
    }
    float inv = 1.0f / lengths[n];
    u32x4 o;
    o.x = (unsigned int)f2b(acc[0] * inv) | ((unsigned int)f2b(acc[1] * inv) << 16);
    o.y = (unsigned int)f2b(acc[2] * inv) | ((unsigned int)f2b(acc[3] * inv) << 16);
    o.z = (unsigned int)f2b(acc[4] * inv) | ((unsigned int)f2b(acc[5] * inv) << 16);
    o.w = (unsigned int)f2b(acc[6] * inv) | ((unsigned int)f2b(acc[7] * inv) << 16);
    *reinterpret_cast<u32x4*>(h0 + (size_t)n * D + g * SCOLS + q * 8) = o;
}

// ---------------------------------------------------------------------------
// A) fused: emb_slice || prep_w
// ---------------------------------------------------------------------------
__global__ __launch_bounds__(256)
void build_aux_kernel(const float* __restrict__ word_emb, unsigned short* __restrict__ ws,
                      const float* __restrict__ W1s, const float* __restrict__ W1n,
                      const float* __restrict__ W2s, const float* __restrict__ W2n,
                      uint4* __restrict__ wf1, uint4* __restrict__ wf2) {
    int b = blockIdx.x;
    if (b < EMB_BLOCKS) {
        emb_body(b, word_emb, ws);
    } else {
        prep_w_body(b - EMB_BLOCKS, W1s, W1n, W2s, W2n, wf1, wf2);
    }
}

// ---------------------------------------------------------------------------
// B) fused: bucket pass1 || pool
// ---------------------------------------------------------------------------
__global__ __launch_bounds__(256)
void pool_pass1_kernel(const int* __restrict__ src, const int* __restrict__ dst,
                       int* __restrict__ bucket_cnt, int2* __restrict__ bucket_buf,
                       const int* __restrict__ wids, const float* __restrict__ lengths,
                       const unsigned short* __restrict__ ws, unsigned short* __restrict__ h0) {
    int b = blockIdx.x;
    if (b < P1_BLOCKS) {
        pass1_body(b, src, dst, bucket_cnt, bucket_buf);
    } else {
        pool_body(b - P1_BLOCKS, wids, lengths, ws, h0);
    }
}

// ---------------------------------------------------------------------------
// C) pass 2: per-bucket padded-CSR tile built in LDS, streamed out coalesced
// ---------------------------------------------------------------------------
__global__ __launch_bounds__(256)
void pass2_kernel(const int* __restrict__ bucket_cnt, const int2* __restrict__ bucket_buf,
                  int* __restrict__ cnt, int* __restrict__ csr_pad) {
    __shared__ int lcnt[RB];            // 1 KB
    __shared__ int lcsr[RB * CAP];      // 48 KB
    int b = blockIdx.x, t = threadIdx.x;
    for (int i = t; i < RB; i += 256) lcnt[i] = 0;
    __syncthreads();
    int ne = bucket_cnt[b];
    if (ne > BCAP) ne = BCAP;
    int lo = b * RB;
    const int2* buf = bucket_buf + (size_t)b * BCAP;
    for (int e = t; e < ne; e += 256) {
        int2 pr = buf[e];
        int p = atomicAdd(&lcnt[pr.x - lo], 1);
        if (p < CAP) lcsr[(pr.x - lo) * CAP + p] = pr.y;
    }
    __syncthreads();
    uint4* dstp = reinterpret_cast<uint4*>(csr_pad + (size_t)lo * CAP);
    const uint4* srcp = reinterpret_cast<const uint4*>(lcsr);
    for (int i = t; i < RB * CAP / 4; i += 256) dstp[i] = srcp[i];
    for (int i = t; i < RB; i += 256)
        if (lo + i < N_NODES) cnt[lo + i] = lcnt[i];
}

// ---------------------------------------------------------------------------
// 6) gather-aggregate (padded CSR), interleaved layout, 16 lanes/node, 4-ILP
// ---------------------------------------------------------------------------
__global__ void gather_agg_kernel(const int* __restrict__ cnt,
                                  const int* __restrict__ csr_pad,
                                  const unsigned short* __restrict__ hI,
                                  unsigned short* __restrict__ aggI) {
    int idx = blockIdx.x * 256 + threadIdx.x;   // 0 .. N*16-1
    int n = idx >> 4, q = idx & 15;             // q = 16B chunk
    if (n >= N_NODES) return;
    const unsigned short* hq = hI + q * 8;
    int dcount = cnt[n];
    int m = dcount < CAP ? dcount : CAP;
    int beg = n * CAP, end = beg + m;
    float acc[8];
#pragma unroll
    for (int j = 0; j < 8; ++j) acc[j] = 0.f;
    int p = beg;
    for (; p + 4 <= end; p += 4) {
        int s0 = csr_pad[p + 0];
        int s1 = csr_pad[p + 1];
        int s2 = csr_pad[p + 2];
        int s3 = csr_pad[p + 3];
        uint4 v0 = *reinterpret_cast<const uint4*>(hq + (size_t)s0 * D);
        uint4 v1 = *reinterpret_cast<const uint4*>(hq + (size_t)s1 * D);
        uint4 v2 = *reinterpret_cast<const uint4*>(hq + (size_t)s2 * D);
        uint4 v3 = *reinterpret_cast<const uint4*>(hq + (size_t)s3 * D);
        acc8(acc, v0); acc8(acc, v1); acc8(acc, v2); acc8(acc, v3);
    }
    for (; p < end; ++p) {
        int s = csr_pad[p];
        acc8(acc, *reinterpret_cast<const uint4*>(hq + (size_t)s * D));
    }
    float inv = 1.0f / (float)(dcount > 1 ? dcount : 1);
    u32x4 o;
    o.x = (unsigned int)f2b(acc[0] * inv) | ((unsigned int)f2b(acc[1] * inv) << 16);
    o.y = (unsigned int)f2b(acc[2] * inv) | ((unsigned int)f2b(acc[3] * inv) << 16);
    o.z = (unsigned int)f2b(acc[4] * inv) | ((unsigned int)f2b(acc[5] * inv) << 16);
    o.w = (unsigned int)f2b(acc[6] * inv) | ((unsigned int)f2b(acc[7] * inv) << 16);
    *reinterpret_cast<u32x4*>(aggI + (size_t)n * D + q * 8) = o;
}

// ---------------------------------------------------------------------------
// 7) out = [h | agg] @ [Ws; Wn] + b  via mfma_f32_16x16x32_bf16 (interleaved).
//    Grid-stride over tile groups (W staged once per block, reused ~3x).
//    In-place (outp==hI, layer 1) safe: each wave loads only its own 16 rows
//    before any store; tile ownership disjoint. No __restrict__.
// ---------------------------------------------------------------------------
template <int RELU, typename OutT>
__global__ __launch_bounds__(256, 2)
void linear_mfma_kernel(const unsigned short* hI, const unsigned short* aggI,
                        const uint4* wfrag, const float* bias, OutT* outp) {
    __shared__ uint4 wlds[4096];   // 64 KB
    int t = threadIdx.x;
#pragma unroll
    for (int i = 0; i < 16; ++i) wlds[t + i * 256] = wfrag[t + i * 256];
    __syncthreads();
    int lane = t & 63, w = t >> 6;
    const int NGRP = (NTILES + 3) / 4;   // 1594
    for (int grp = blockIdx.x; grp < NGRP; grp += LIN_BLOCKS) {
        int rt = grp * 4 + w;
        if (rt >= NTILES) continue;
        int row0 = rt * 16;
        int arow = row0 + (lane & 15);
        int koff = (lane >> 4) * 8;
        const unsigned short* hp = hI + (size_t)arow * D + koff;
        const unsigned short* ap = aggI + (size_t)arow * D + koff;
        bf16x8 a[8];
#pragma unroll
        for (int ks = 0; ks < 4; ++ks) a[ks] = *reinterpret_cast<const bf16x8*>(hp + ks * 32);
#pragma unroll
        for (int ks = 0; ks < 4; ++ks) a[4 + ks] = *reinterpret_cast<const bf16x8*>(ap + ks * 32);
        int crow = row0 + (lane >> 4) * 4;
        int ccol0 = lane & 15;
#pragma unroll
        for (int ct = 0; ct < 8; ++ct) {
            f32x4 acc = {0.f, 0.f, 0.f, 0.f};
#pragma unroll
            for (int ks = 0; ks < 8; ++ks) {
                bf16x8 b = *reinterpret_cast<const bf16x8*>(&wlds[(ks * 8 + ct) * 64 + lane]);
                acc = __builtin_amdgcn_mfma_f32_16x16x32_bf16(a[ks], b, acc, 0, 0, 0);
            }
            int col = ct * 16 + ccol0;
            float bv = bias[col];
#pragma unroll
            for (int i = 0; i < 4; ++i) {
                float v = acc[i] + bv;
                if (RELU) v = (v > 0.f) ? v : NEG_SLOPE * v;
                if constexpr (sizeof(OutT) == 2) {
                    outp[(size_t)(crow + i) * D + col] = (OutT)f2b(v);
                } else {
                    outp[(size_t)(crow + i) * D + col] = v;
                }
            }
        }
    }
}

extern "C" void kernel_launch(void* const* d_in, const int* in_sizes, int n_in,
                              void* d_out, int out_size, void* d_ws, size_t ws_size,
                              hipStream_t stream) {
    const int*   wids     = (const int*)d_in[0];
    const float* lengths  = (const float*)d_in[1];
    const int*   src      = (const int*)d_in[2];
    const int*   dst      = (const int*)d_in[3];
    const float* word_emb = (const float*)d_in[4];
    const float* W1s      = (const float*)d_in[5];
    const float* W1n      = (const float*)d_in[6];
    const float* b1       = (const float*)d_in[7];
    const float* W2s      = (const float*)d_in[8];
    const float* W2n      = (const float*)d_in[9];
    const float* b2       = (const float*)d_in[10];

    // d_ws layout
    unsigned short* h0  = (unsigned short*)d_ws;               // N*D bf16
    unsigned short* agg = h0 + (size_t)N_NODES * D;            // N*D bf16
    uint4* wf1 = (uint4*)(agg + (size_t)N_NODES * D);          // 4096 uint4
    uint4* wf2 = wf1 + 4096;                                   // 4096 uint4
    int* cnt        = (int*)(wf2 + 4096);                      // N
    int* bucket_cnt = cnt + N_NODES;                           // NBUCK

    // d_out staging (dead until the final layer-2 write):
    //   [0, 7.7MB): bf16 sliced emb
    //   [8MB, 8+19.7MB): padded CSR (csr_pad)
    //   [28MB, 28+9.4MB): bucket_buf (int2 pairs)
    unsigned short* ws_emb = (unsigned short*)d_out;
    int*  csr_pad    = (int*)((char*)d_out + (8u << 20));
    int2* bucket_buf = (int2*)((char*)d_out + (28u << 20));

    (void)hipMemsetAsync(bucket_cnt, 0, NBUCK * sizeof(int), stream);

    // A: emb_slice || prep_w
    build_aux_kernel<<<EMB_BLOCKS + PREP_BLOCKS, 256, 0, stream>>>(
        word_emb, ws_emb, W1s, W1n, W2s, W2n, wf1, wf2);

    // B: bucket pass1 || pool
    pool_pass1_kernel<<<P1_BLOCKS + POOL_BLOCKS, 256, 0, stream>>>(
        src, dst, bucket_cnt, bucket_buf, wids, lengths, ws_emb, h0);

    // C: per-bucket CSR tiles in LDS -> coalesced csr_pad + cnt
    pass2_kernel<<<NBUCK, 256, 0, stream>>>(bucket_cnt, bucket_buf, cnt, csr_pad);

    const int GATHER_GRID = (N_NODES * 16) / 256;              // 6375
    // layer 1 (in-place h0 -> h0)
    gather_agg_kernel<<<GATHER_GRID, 256, 0, stream>>>(cnt, csr_pad, h0, agg);
    linear_mfma_kernel<1, unsigned short><<<LIN_BLOCKS, 256, 0, stream>>>(h0, agg, wf1, b1, h0);
    // layer 2 (f32 out -> d_out; all staging regions dead by then)
    gather_agg_kernel<<<GATHER_GRID, 256, 0, stream>>>(cnt, csr_pad, h0, agg);
    linear_mfma_kernel<0, float><<<LIN_BLOCKS, 256, 0, stream>>>(h0, agg, wf2, b2, (float*)d_out);
}

// Round 18
// 202.943 us; speedup vs baseline: 1.3915x; 1.0719x over previous
//
#include <hip/hip_runtime.h>

#define N_NODES 102000
#define D 128
#define L 12
#define E_EDGES 1000000
#define V_VOCAB 30001            // rows in word_emb (incl. padding row)
#define NEG_SLOPE 0.01f
#define NTILES (N_NODES / 16)    // 6375 exact

// padded CSR: fixed CAP slots per node (deg ~ Poisson(9.8); P(deg>=48)~2e-18)
#define CAP 48

// bucketed CSR build
#define RB 256                                    // nodes per bucket
#define NBUCK ((N_NODES + RB - 1) / RB)           // 399
#define BCAP 2944                                 // mean 2510 + ~8.7 sigma
#define EPT 16                                    // edges per thread in pass1
#define EPB (256 * EPT)                           // 4096 edges per block
#define P1_BLOCKS ((E_EDGES + EPB - 1) / EPB)     // 245

// pool slicing: 4 slices x 32 bf16 cols (one 64-B line per emb row-slice)
#define NSLC 4
#define SCOLS 32
#define WS2_STRIDE ((size_t)V_VOCAB * SCOLS)      // bf16 elems per emb slice

// fused-kernel block ranges
#define EMB_BLOCKS ((V_VOCAB * 16 + 255) / 256)   // 1876
#define PREP_BLOCKS 32
#define POOL_BLOCKS (NSLC * ((N_NODES * 4 + 255) / 256))  // 6376

#define LIN_BLOCKS 512

typedef __attribute__((ext_vector_type(8))) short bf16x8;
typedef __attribute__((ext_vector_type(4))) float f32x4;
typedef __attribute__((ext_vector_type(4))) int i32x4;
typedef __attribute__((ext_vector_type(4))) unsigned int u32x4;

__device__ __forceinline__ float b2f(unsigned short u) {
    union { float f; unsigned int i; } x; x.i = ((unsigned int)u) << 16; return x.f;
}
__device__ __forceinline__ unsigned short f2b(float f) {
    unsigned int x = __float_as_uint(f);
    unsigned int r = (x + 0x7fffu + ((x >> 16) & 1u)) >> 16;
    return (unsigned short)r;
}
__device__ __forceinline__ void acc8(float* acc, uint4 v) {
    acc[0] += b2f((unsigned short)(v.x & 0xffff)); acc[1] += b2f((unsigned short)(v.x >> 16));
    acc[2] += b2f((unsigned short)(v.y & 0xffff)); acc[3] += b2f((unsigned short)(v.y >> 16));
    acc[4] += b2f((unsigned short)(v.z & 0xffff)); acc[5] += b2f((unsigned short)(v.z >> 16));
    acc[6] += b2f((unsigned short)(v.w & 0xffff)); acc[7] += b2f((unsigned short)(v.w >> 16));
}

// ---------------------------------------------------------------------------
// device bodies
// ---------------------------------------------------------------------------
__device__ void emb_body(int b, const float* __restrict__ word_emb,
                         unsigned short* __restrict__ ws) {
    int id = b * 256 + threadIdx.x;
    if (id >= V_VOCAB * 16) return;
    int r = id >> 4, q = id & 15;
    const float* p = word_emb + (size_t)r * D + q * 8;
    float4 v0 = *reinterpret_cast<const float4*>(p);
    float4 v1 = *reinterpret_cast<const float4*>(p + 4);
    u32x4 o;
    o.x = (unsigned int)f2b(v0.x) | ((unsigned int)f2b(v0.y) << 16);
    o.y = (unsigned int)f2b(v0.z) | ((unsigned int)f2b(v0.w) << 16);
    o.z = (unsigned int)f2b(v1.x) | ((unsigned int)f2b(v1.y) << 16);
    o.w = (unsigned int)f2b(v1.z) | ((unsigned int)f2b(v1.w) << 16);
    int s = q >> 2, inner = (q & 3) * 8;
    *reinterpret_cast<u32x4*>(ws + (size_t)s * WS2_STRIDE + (size_t)r * SCOLS + inner) = o;
}

__device__ void prep_w_body(int b, const float* __restrict__ W1s, const float* __restrict__ W1n,
                            const float* __restrict__ W2s, const float* __restrict__ W2n,
                            uint4* __restrict__ wf1, uint4* __restrict__ wf2) {
    int tid = b * 256 + threadIdx.x;   // 0..8191
    int layer = tid >> 12;
    int rem = tid & 4095;
    int ks = rem >> 9;
    int ct = (rem >> 6) & 7;
    int lane = rem & 63;
    const float* Ws = layer ? W2s : W1s;
    const float* Wn = layer ? W2n : W1n;
    uint4* outp = layer ? wf2 : wf1;
    int r0 = ks * 32 + (lane >> 4) * 8;
    int c = ct * 16 + (lane & 15);
    unsigned short e[8];
#pragma unroll
    for (int j = 0; j < 8; ++j) {
        int r = r0 + j;
        float v = (r < 128) ? Ws[r * 128 + c] : Wn[(r - 128) * 128 + c];
        e[j] = f2b(v);
    }
    uint4 o;
    o.x = (unsigned int)e[0] | ((unsigned int)e[1] << 16);
    o.y = (unsigned int)e[2] | ((unsigned int)e[3] << 16);
    o.z = (unsigned int)e[4] | ((unsigned int)e[5] << 16);
    o.w = (unsigned int)e[6] | ((unsigned int)e[7] << 16);
    outp[(ks * 8 + ct) * 64 + lane] = o;
}

// pass 1: LDS-histogram bucket append, 16 edges/thread (large runs -> few lines)
__device__ void pass1_body(int b, const int* __restrict__ src, const int* __restrict__ dst,
                           int* __restrict__ bucket_cnt, int2* __restrict__ bucket_buf) {
    __shared__ int hist[NBUCK];
    __shared__ int base[NBUCK];
    int t = threadIdx.x;
    for (int i = t; i < NBUCK; i += 256) hist[i] = 0;
    __syncthreads();
    int e0 = b * EPB + t * EPT;
    i32x4 d4[4], s4[4];
    bool qv[4];
#pragma unroll
    for (int j = 0; j < 4; ++j) {
        int e = e0 + j * 4;
        qv[j] = (e + 4 <= E_EDGES);          // E % 4 == 0 -> quad all-or-nothing
        if (qv[j]) {
            d4[j] = __builtin_nontemporal_load(reinterpret_cast<const i32x4*>(dst + e));
            s4[j] = __builtin_nontemporal_load(reinterpret_cast<const i32x4*>(src + e));
            atomicAdd(&hist[d4[j].x >> 8], 1);
            atomicAdd(&hist[d4[j].y >> 8], 1);
            atomicAdd(&hist[d4[j].z >> 8], 1);
            atomicAdd(&hist[d4[j].w >> 8], 1);
        }
    }
    __syncthreads();
    for (int i = t; i < NBUCK; i += 256) {
        int h = hist[i];
        base[i] = h ? atomicAdd(&bucket_cnt[i], h) : 0;
        hist[i] = 0;                        // reuse as cursor
    }
    __syncthreads();
#pragma unroll
    for (int j = 0; j < 4; ++j) {
        if (qv[j]) {
            int bb, p;
            bb = d4[j].x >> 8; p = base[bb] + atomicAdd(&hist[bb], 1);
            if (p < BCAP) bucket_buf[(size_t)bb * BCAP + p] = make_int2(d4[j].x, s4[j].x);
            bb = d4[j].y >> 8; p = base[bb] + atomicAdd(&hist[bb], 1);
            if (p < BCAP) bucket_buf[(size_t)bb * BCAP + p] = make_int2(d4[j].y, s4[j].y);
            bb = d4[j].z >> 8; p = base[bb] + atomicAdd(&hist[bb], 1);
            if (p < BCAP) bucket_buf[(size_t)bb * BCAP + p] = make_int2(d4[j].z, s4[j].z);
            bb = d4[j].w >> 8; p = base[bb] + atomicAdd(&hist[bb], 1);
            if (p < BCAP) bucket_buf[(size_t)bb * BCAP + p] = make_int2(d4[j].w, s4[j].w);
        }
    }
}

__device__ void pool_body(int b, const int* __restrict__ wids,
                          const float* __restrict__ lengths,
                          const unsigned short* __restrict__ ws,
                          unsigned short* __restrict__ h0) {
    int g = b & (NSLC - 1);
    int idx = (b >> 2) * 256 + threadIdx.x;
    if (idx >= N_NODES * 4) return;
    int n = idx >> 2, q = idx & 3;
    const i32x4* wp = reinterpret_cast<const i32x4*>(wids + n * L);
    i32x4 w0 = __builtin_nontemporal_load(wp + 0);
    i32x4 w1 = __builtin_nontemporal_load(wp + 1);
    i32x4 w2 = __builtin_nontemporal_load(wp + 2);
    int wid[L] = {w0.x, w0.y, w0.z, w0.w, w1.x, w1.y, w1.z, w1.w, w2.x, w2.y, w2.z, w2.w};
    const unsigned short* wsg = ws + (size_t)g * WS2_STRIDE + q * 8;
    float acc[8];
#pragma unroll
    for (int j = 0; j < 8; ++j) acc[j] = 0.f;
#pragma unroll
    for (int l = 0; l < L; ++l) {
        uint4 v = *reinterpret_cast<const uint4*>(wsg + (size_t)wid[l] * SCOLS);
        acc8(acc, v);
    }
    float inv = 1.0f / lengths[n];
    u32x4 o;
    o.x = (unsigned int)f2b(acc[0] * inv) | ((unsigned int)f2b(acc[1] * inv) << 16);
    o.y = (unsigned int)f2b(acc[2] * inv) | ((unsigned int)f2b(acc[3] * inv) << 16);
    o.z = (unsigned int)f2b(acc[4] * inv) | ((unsigned int)f2b(acc[5] * inv) << 16);
    o.w = (unsigned int)f2b(acc[6] * inv) | ((unsigned int)f2b(acc[7] * inv) << 16);
    *reinterpret_cast<u32x4*>(h0 + (size_t)n * D + g * SCOLS + q * 8) = o;
}

// ---------------------------------------------------------------------------
// A) fused: emb_slice || prep_w
// ---------------------------------------------------------------------------
__global__ __launch_bounds__(256)
void build_aux_kernel(const float* __restrict__ word_emb, unsigned short* __restrict__ ws,
                      const float* __restrict__ W1s, const float* __restrict__ W1n,
                      const float* __restrict__ W2s, const float* __restrict__ W2n,
                      uint4* __restrict__ wf1, uint4* __restrict__ wf2) {
    int b = blockIdx.x;
    if (b < EMB_BLOCKS) {
        emb_body(b, word_emb, ws);
    } else {
        prep_w_body(b - EMB_BLOCKS, W1s, W1n, W2s, W2n, wf1, wf2);
    }
}

// ---------------------------------------------------------------------------
// B) fused: bucket pass1 || pool
// ---------------------------------------------------------------------------
__global__ __launch_bounds__(256)
void pool_pass1_kernel(const int* __restrict__ src, const int* __restrict__ dst,
                       int* __restrict__ bucket_cnt, int2* __restrict__ bucket_buf,
                       const int* __restrict__ wids, const float* __restrict__ lengths,
                       const unsigned short* __restrict__ ws, unsigned short* __restrict__ h0) {
    int b = blockIdx.x;
    if (b < P1_BLOCKS) {
        pass1_body(b, src, dst, bucket_cnt, bucket_buf);
    } else {
        pool_body(b - P1_BLOCKS, wids, lengths, ws, h0);
    }
}

// ---------------------------------------------------------------------------
// C) pass 2: per-bucket padded-CSR tile built in LDS, streamed out coalesced
// ---------------------------------------------------------------------------
__global__ __launch_bounds__(256)
void pass2_kernel(const int* __restrict__ bucket_cnt, const int2* __restrict__ bucket_buf,
                  int* __restrict__ cnt, int* __restrict__ csr_pad) {
    __shared__ int lcnt[RB];            // 1 KB
    __shared__ int lcsr[RB * CAP];      // 48 KB
    int b = blockIdx.x, t = threadIdx.x;
    for (int i = t; i < RB; i += 256) lcnt[i] = 0;
    __syncthreads();
    int ne = bucket_cnt[b];
    if (ne > BCAP) ne = BCAP;
    int lo = b * RB;
    const int2* buf = bucket_buf + (size_t)b * BCAP;
    for (int e = t; e < ne; e += 256) {
        int2 pr = buf[e];
        int p = atomicAdd(&lcnt[pr.x - lo], 1);
        if (p < CAP) lcsr[(pr.x - lo) * CAP + p] = pr.y;
    }
    __syncthreads();
    uint4* dstp = reinterpret_cast<uint4*>(csr_pad + (size_t)lo * CAP);
    const uint4* srcp = reinterpret_cast<const uint4*>(lcsr);
    for (int i = t; i < RB * CAP / 4; i += 256) dstp[i] = srcp[i];
    for (int i = t; i < RB; i += 256)
        if (lo + i < N_NODES) cnt[lo + i] = lcnt[i];
}

// ---------------------------------------------------------------------------
// 6) gather-aggregate (padded CSR), interleaved layout, 16 lanes/node, 4-ILP
// ---------------------------------------------------------------------------
__global__ void gather_agg_kernel(const int* __restrict__ cnt,
                                  const int* __restrict__ csr_pad,
                                  const unsigned short* __restrict__ hI,
                                  unsigned short* __restrict__ aggI) {
    int idx = blockIdx.x * 256 + threadIdx.x;   // 0 .. N*16-1
    int n = idx >> 4, q = idx & 15;             // q = 16B chunk
    if (n >= N_NODES) return;
    const unsigned short* hq = hI + q * 8;
    int dcount = cnt[n];
    int m = dcount < CAP ? dcount : CAP;
    int beg = n * CAP, end = beg + m;
    float acc[8];
#pragma unroll
    for (int j = 0; j < 8; ++j) acc[j] = 0.f;
    int p = beg;
    for (; p + 4 <= end; p += 4) {
        int s0 = csr_pad[p + 0];
        int s1 = csr_pad[p + 1];
        int s2 = csr_pad[p + 2];
        int s3 = csr_pad[p + 3];
        uint4 v0 = *reinterpret_cast<const uint4*>(hq + (size_t)s0 * D);
        uint4 v1 = *reinterpret_cast<const uint4*>(hq + (size_t)s1 * D);
        uint4 v2 = *reinterpret_cast<const uint4*>(hq + (size_t)s2 * D);
        uint4 v3 = *reinterpret_cast<const uint4*>(hq + (size_t)s3 * D);
        acc8(acc, v0); acc8(acc, v1); acc8(acc, v2); acc8(acc, v3);
    }
    for (; p < end; ++p) {
        int s = csr_pad[p];
        acc8(acc, *reinterpret_cast<const uint4*>(hq + (size_t)s * D));
    }
    float inv = 1.0f / (float)(dcount > 1 ? dcount : 1);
    u32x4 o;
    o.x = (unsigned int)f2b(acc[0] * inv) | ((unsigned int)f2b(acc[1] * inv) << 16);
    o.y = (unsigned int)f2b(acc[2] * inv) | ((unsigned int)f2b(acc[3] * inv) << 16);
    o.z = (unsigned int)f2b(acc[4] * inv) | ((unsigned int)f2b(acc[5] * inv) << 16);
    o.w = (unsigned int)f2b(acc[6] * inv) | ((unsigned int)f2b(acc[7] * inv) << 16);
    *reinterpret_cast<u32x4*>(aggI + (size_t)n * D + q * 8) = o;
}

// ---------------------------------------------------------------------------
// 7) out = [h | agg] @ [Ws; Wn] + b  via mfma_f32_16x16x32_bf16 (interleaved).
//    Grid-stride over tile groups (W staged once per block, reused ~3x).
//    In-place (outp==hI, layer 1) safe: each wave loads only its own 16 rows
//    before any store; tile ownership disjoint. No __restrict__.
// ---------------------------------------------------------------------------
template <int RELU, typename OutT>
__global__ __launch_bounds__(256, 2)
void linear_mfma_kernel(const unsigned short* hI, const unsigned short* aggI,
                        const uint4* wfrag, const float* bias, OutT* outp) {
    __shared__ uint4 wlds[4096];   // 64 KB
    int t = threadIdx.x;
#pragma unroll
    for (int i = 0; i < 16; ++i) wlds[t + i * 256] = wfrag[t + i * 256];
    __syncthreads();
    int lane = t & 63, w = t >> 6;
    const int NGRP = (NTILES + 3) / 4;   // 1594
    for (int grp = blockIdx.x; grp < NGRP; grp += LIN_BLOCKS) {
        int rt = grp * 4 + w;
        if (rt >= NTILES) continue;
        int row0 = rt * 16;
        int arow = row0 + (lane & 15);
        int koff = (lane >> 4) * 8;
        const unsigned short* hp = hI + (size_t)arow * D + koff;
        const unsigned short* ap = aggI + (size_t)arow * D + koff;
        bf16x8 a[8];
#pragma unroll
        for (int ks = 0; ks < 4; ++ks) a[ks] = *reinterpret_cast<const bf16x8*>(hp + ks * 32);
#pragma unroll
        for (int ks = 0; ks < 4; ++ks) a[4 + ks] = *reinterpret_cast<const bf16x8*>(ap + ks * 32);
        int crow = row0 + (lane >> 4) * 4;
        int ccol0 = lane & 15;
#pragma unroll
        for (int ct = 0; ct < 8; ++ct) {
            f32x4 acc = {0.f, 0.f, 0.f, 0.f};
#pragma unroll
            for (int ks = 0; ks < 8; ++ks) {
                bf16x8 b = *reinterpret_cast<const bf16x8*>(&wlds[(ks * 8 + ct) * 64 + lane]);
                acc = __builtin_amdgcn_mfma_f32_16x16x32_bf16(a[ks], b, acc, 0, 0, 0);
            }
            int col = ct * 16 + ccol0;
            float bv = bias[col];
#pragma unroll
            for (int i = 0; i < 4; ++i) {
                float v = acc[i] + bv;
                if (RELU) v = (v > 0.f) ? v : NEG_SLOPE * v;
                if constexpr (sizeof(OutT) == 2) {
                    outp[(size_t)(crow + i) * D + col] = (OutT)f2b(v);
                } else {
                    outp[(size_t)(crow + i) * D + col] = v;
                }
            }
        }
    }
}

extern "C" void kernel_launch(void* const* d_in, const int* in_sizes, int n_in,
                              void* d_out, int out_size, void* d_ws, size_t ws_size,
                              hipStream_t stream) {
    const int*   wids     = (const int*)d_in[0];
    const float* lengths  = (const float*)d_in[1];
    const int*   src      = (const int*)d_in[2];
    const int*   dst      = (const int*)d_in[3];
    const float* word_emb = (const float*)d_in[4];
    const float* W1s      = (const float*)d_in[5];
    const float* W1n      = (const float*)d_in[6];
    const float* b1       = (const float*)d_in[7];
    const float* W2s      = (const float*)d_in[8];
    const float* W2n      = (const float*)d_in[9];
    const float* b2       = (const float*)d_in[10];

    // d_ws layout
    unsigned short* h0  = (unsigned short*)d_ws;               // N*D bf16
    unsigned short* agg = h0 + (size_t)N_NODES * D;            // N*D bf16
    uint4* wf1 = (uint4*)(agg + (size_t)N_NODES * D);          // 4096 uint4
    uint4* wf2 = wf1 + 4096;                                   // 4096 uint4
    int* cnt        = (int*)(wf2 + 4096);                      // N
    int* bucket_cnt = cnt + N_NODES;                           // NBUCK

    // d_out staging (dead until the final layer-2 write):
    //   [0, 7.7MB): bf16 sliced emb
    //   [8MB, 8+19.7MB): padded CSR (csr_pad)
    //   [28MB, 28+9.4MB): bucket_buf (int2 pairs)
    unsigned short* ws_emb = (unsigned short*)d_out;
    int*  csr_pad    = (int*)((char*)d_out + (8u << 20));
    int2* bucket_buf = (int2*)((char*)d_out + (28u << 20));

    (void)hipMemsetAsync(bucket_cnt, 0, NBUCK * sizeof(int), stream);

    // A: emb_slice || prep_w
    build_aux_kernel<<<EMB_BLOCKS + PREP_BLOCKS, 256, 0, stream>>>(
        word_emb, ws_emb, W1s, W1n, W2s, W2n, wf1, wf2);

    // B: bucket pass1 || pool
    pool_pass1_kernel<<<P1_BLOCKS + POOL_BLOCKS, 256, 0, stream>>>(
        src, dst, bucket_cnt, bucket_buf, wids, lengths, ws_emb, h0);

    // C: per-bucket CSR tiles in LDS -> coalesced csr_pad + cnt
    pass2_kernel<<<NBUCK, 256, 0, stream>>>(bucket_cnt, bucket_buf, cnt, csr_pad);

    const int GATHER_GRID = (N_NODES * 16) / 256;              // 6375
    // layer 1 (in-place h0 -> h0)
    gather_agg_kernel<<<GATHER_GRID, 256, 0, stream>>>(cnt, csr_pad, h0, agg);
    linear_mfma_kernel<1, unsigned short><<<LIN_BLOCKS, 256, 0, stream>>>(h0, agg, wf1, b1, h0);
    // layer 2 (f32 out -> d_out; all staging regions dead by then)
    gather_agg_kernel<<<GATHER_GRID, 256, 0, stream>>>(cnt, csr_pad, h0, agg);
    linear_mfma_kernel<0, float><<<LIN_BLOCKS, 256, 0, stream>>>(h0, agg, wf2, b2, (float*)d_out);
}